// Round 6
// baseline (207.298 us; speedup 1.0000x reference)
//
#include <hip/hip_runtime.h>

// Problem constants (match reference)
static constexpr int NN   = 65536;   // total nodes
static constexpr int NPG  = 256;     // nodes per graph
static constexpr int NB   = 256;     // graphs (batch)
static constexpr int EMB  = 128;     // gcn emb dim
static constexpr int NOUT = 512;     // n_embd

static constexpr int NBIN = 256;     // partitions over dst>>8 (256 nodes each)
static constexpr int CAP  = 4608;    // bin capacity: mean 4096 edges, +8 sigma
static constexpr int SCAP = CAP + 256; // sorted capacity incl. even-padding holes

// Head GEMM tiling: merged owner-block kernel, bit-identical regrouped sum
static constexpr int KS  = 16;       // s-partials (kept for identical order)
static constexpr int IC  = NPG / KS; // 16 i per s-partial
static constexpr int BT2 = 4;        // batches per block (merged head)

// clang-native float4 for nontemporal builtins (HIP_vector_type is rejected)
typedef float nfloat4 __attribute__((ext_vector_type(4)));

// Fused partition (blocks 0..255) + buildV (blocks 256..511, 1 V-row each,
// nontemporal float4 W3 loads). V4[i][j] = float4( sum_c W2[k][c]*W3[i*128+c][j],
// k=0..2, b2-row in .w ). packed edge = src | (dst&255)<<16
// Partition output: per-block contiguous (coalesced) + packed (loff|cnt<<16)
// descriptors in cl[blk*NBIN+bin]; no global atomics, no memset needed.
__global__ __launch_bounds__(1024)
void k_partV(const int* __restrict__ src, const int* __restrict__ dst, int E,
             int* __restrict__ part, int* __restrict__ cl,
             const float* __restrict__ W2, const float* __restrict__ b2,
             const float* __restrict__ W3, float4* __restrict__ V4) {
    union SH {
        struct { int hist[NBIN]; int loff[NBIN]; int scanbuf[NBIN];
                 int stage[4096]; } part;                           // ~19.5 KB
        float4 red[8][4][128];                                      // 64 KB
    };
    __shared__ SH sh;
    int tid = threadIdx.x;
    int bid = blockIdx.x;

    if (bid >= NBIN) {
        // ---- buildV role: one i-row, 8 c-groups of 16, nontemporal loads ----
        int i  = bid - NBIN;
        int j4 = tid & 127;
        int cg = tid >> 7;
        const nfloat4* w3 = (const nfloat4*)(W3 + (size_t)i * EMB * NOUT)
                            + (size_t)cg * 16 * (NOUT/4) + j4;
        float4 a0 = {0,0,0,0}, a1 = {0,0,0,0}, a2 = {0,0,0,0}, a3 = {0,0,0,0};
        for (int c = 0; c < 16; c++) {
            nfloat4 v = __builtin_nontemporal_load(&w3[(size_t)c * (NOUT/4)]);
            int cc = cg*16 + c;
            float w0 = W2[0*EMB+cc], w1 = W2[1*EMB+cc], w2 = W2[2*EMB+cc], wb = b2[cc];
            a0.x += w0*v.x; a0.y += w0*v.y; a0.z += w0*v.z; a0.w += w0*v.w;
            a1.x += w1*v.x; a1.y += w1*v.y; a1.z += w1*v.z; a1.w += w1*v.w;
            a2.x += w2*v.x; a2.y += w2*v.y; a2.z += w2*v.z; a2.w += w2*v.w;
            a3.x += wb*v.x; a3.y += wb*v.y; a3.z += wb*v.z; a3.w += wb*v.w;
        }
        sh.red[cg][0][j4] = a0;
        sh.red[cg][1][j4] = a1;
        sh.red[cg][2][j4] = a2;
        sh.red[cg][3][j4] = a3;
        __syncthreads();
        if (tid < 512) {
            int k = tid >> 7, jj = tid & 127;
            float4 s = sh.red[0][k][jj];
#pragma unroll
            for (int g = 1; g < 8; g++) {
                float4 v = sh.red[g][k][jj];
                s.x += v.x; s.y += v.y; s.z += v.z; s.w += v.w;
            }
            sh.red[0][k][jj] = s;
        }
        __syncthreads();
        if (tid < NOUT) {
            int j = tid;
            const float* r0 = (const float*)&sh.red[0][0][j >> 2];
            const float* r1 = (const float*)&sh.red[0][1][j >> 2];
            const float* r2 = (const float*)&sh.red[0][2][j >> 2];
            const float* r3 = (const float*)&sh.red[0][3][j >> 2];
            float4 o = { r0[j & 3], r1[j & 3], r2[j & 3], r3[j & 3] };
            V4[(size_t)i * NOUT + j] = o;
        }
        return;
    }
    // ---- partition role: radix by dst>>8, LDS count+rank, contiguous out ----
    int epb = (E + NBIN - 1) / NBIN;          // 4096 for E=1M
    int e0 = bid * epb;
    int e1 = min(e0 + epb, E);
    if (tid < NBIN) sh.part.hist[tid] = 0;
    __syncthreads();

    int pk[4], bn[4], rk[4];
    int n = 0;
    int e = e0 + tid * 4;
    if (e + 4 <= e1) {
        int4 s4 = *(const int4*)(src + e);
        int4 d4 = *(const int4*)(dst + e);
        int ss[4] = {s4.x, s4.y, s4.z, s4.w};
        int dd[4] = {d4.x, d4.y, d4.z, d4.w};
#pragma unroll
        for (int k = 0; k < 4; k++) {
            pk[k] = ss[k] | ((dd[k] & 255) << 16);
            bn[k] = dd[k] >> 8;
            rk[k] = atomicAdd(&sh.part.hist[bn[k]], 1);
        }
        n = 4;
    } else {
        for (int k = 0; k < 4 && e + k < e1; k++) {
            int s = src[e+k], d = dst[e+k];
            pk[n] = s | ((d & 255) << 16);
            bn[n] = d >> 8;
            rk[n] = atomicAdd(&sh.part.hist[bn[n]], 1);
            n++;
        }
    }
    __syncthreads();

    if (tid < NBIN) sh.part.scanbuf[tid] = sh.part.hist[tid];
    __syncthreads();
    for (int off = 1; off < NBIN; off <<= 1) {
        int v = 0;
        if (tid < NBIN && tid >= off) v = sh.part.scanbuf[tid - off];
        __syncthreads();
        if (tid < NBIN) sh.part.scanbuf[tid] += v;
        __syncthreads();
    }
    if (tid < NBIN) {
        int lo = sh.part.scanbuf[tid] - sh.part.hist[tid];
        sh.part.loff[tid] = lo;
        cl[bid * NBIN + tid] = lo | (sh.part.hist[tid] << 16);  // coalesced
    }
    __syncthreads();

    for (int k = 0; k < n; k++) sh.part.stage[sh.part.loff[bn[k]] + rk[k]] = pk[k];
    __syncthreads();

    int ctot = e1 - e0;                       // all edges staged, dense
    for (int t = tid; t < ctot; t += 1024)
        part[(size_t)bid * epb + t] = sh.part.stage[t];         // coalesced
}

// Per-bin CSR build (counting sort by dst) + degprep fused. 512 threads.
// Gathers this bin's edge segments from all 256 partition blocks using the
// packed (loff|cnt) descriptors; per-blk bases via 64-wide wave scan.
// Node starts even-padded so neighbor lists are uint-aligned for the gathers.
__global__ __launch_bounds__(512)
void k_csr(const int* __restrict__ cl, const int* __restrict__ part, int epb,
           const float* __restrict__ nodes,
           float* __restrict__ dinv, float4* __restrict__ y1,
           int* __restrict__ rs, unsigned short* __restrict__ srt) {
    __shared__ int pkst[CAP];
    __shared__ int hist[NPG], off_[NPG];
    __shared__ int wtot[4];
    __shared__ int cls[NBIN], blo[NBIN];
    __shared__ unsigned short stageS[SCAP];
    int tid = threadIdx.x, bin = blockIdx.x;
    if (tid < NPG) hist[tid] = 0;

    // per-blk counts for this bin; exclusive scan over 256 blks
    int cn = 0, v = 0;
    if (tid < NBIN) {
        int c = cl[tid * NBIN + bin];
        cls[tid] = c;
        cn = c >> 16;
        v = cn;
    }
    int lane = tid & 63;
#pragma unroll
    for (int off = 1; off < 64; off <<= 1) {
        int t = __shfl_up(v, off, 64);
        if (tid < NBIN && lane >= off) v += t;
    }
    if (tid < NBIN && lane == 63) wtot[tid >> 6] = v;
    __syncthreads();                                   // B1
    if (tid < NBIN) {
        int wv = tid >> 6, offs = 0;
#pragma unroll
        for (int w = 0; w < 3; w++) if (w < wv) offs += wtot[w];
        blo[tid] = v + offs - cn;                      // exclusive base
    }
    __syncthreads();                                   // B2

    // copy + per-node count: 2 threads per partition block
    {
        int blk = tid >> 1, half = tid & 1;
        int c = cls[blk];
        int lo = c & 0xFFFF, cb = c >> 16;
        int db = blo[blk];
        const int* q = part + (size_t)blk * epb + lo;
        for (int t = half; t < cb; t += 2) {
            int d2 = db + t;
            if (d2 < CAP) {
                int p = q[t];
                pkst[d2] = p;
                atomicAdd(&hist[(p >> 16) & 255], 1);
            }
        }
    }
    __syncthreads();                                   // B3

    // wave-scan of even-padded per-node counts
    int h = 0, v2 = 0;
    if (tid < NPG) { h = hist[tid]; v2 = (h + 1) & ~1; }
#pragma unroll
    for (int off = 1; off < 64; off <<= 1) {
        int t = __shfl_up(v2, off, 64);
        if (tid < NPG && lane >= off) v2 += t;
    }
    if (tid < NPG && lane == 63) wtot[tid >> 6] = v2;
    __syncthreads();
    if (tid < NPG) {
        int wv = tid >> 6;
        int offs = 0;
#pragma unroll
        for (int w = 0; w < 3; w++) if (w < wv) offs += wtot[w];
        int start = v2 + offs - ((h + 1) & ~1);     // exclusive even-padded start
        off_[tid] = start;
        int node = bin * NPG + tid;
        float di = rsqrtf((float)(h + 1));          // +1 self-loop
        dinv[node] = di;
        y1[node] = make_float4(nodes[3*node+0] * di, nodes[3*node+1] * di,
                               nodes[3*node+2] * di, 0.f);
        rs[node] = start | (h << 20);
    }
    __syncthreads();
    int rawtot = blo[NBIN-1] + (cls[NBIN-1] >> 16);
    if (rawtot > CAP) rawtot = CAP;
    for (int e2 = tid; e2 < rawtot; e2 += 512) {
        int p = pkst[e2];
        int pos = atomicAdd(&off_[(p >> 16) & 255], 1);
        stageS[pos] = (unsigned short)(p & 0xFFFF);
    }
    __syncthreads();
    int tot = wtot[0] + wtot[1] + wtot[2] + wtot[3];   // even-padded total
    const unsigned int* so = (const unsigned int*)stageS;
    unsigned int* g = (unsigned int*)(srt + (size_t)bin * SCAP);
    for (int t = tid; t < (tot >> 1); t += 512) g[t] = so[t];
}

// Octet-per-node CSR gather: one coalesced uint = 2 neighbor ids per lane,
// both y-gathers issue independently (1 dependent round instead of 2).
__device__ __forceinline__ void agg_pass(int g, const int* __restrict__ rs,
                                         const unsigned short* __restrict__ srt,
                                         const float* __restrict__ dinv,
                                         const float* __restrict__ W1,
                                         const float* __restrict__ b1,
                                         const float4* __restrict__ yin,
                                         float4* __restrict__ yout, bool first) {
    int i = g >> 3, sub = g & 7;
    int rsd = rs[i];
    int start = rsd & 0xFFFFF, deg = rsd >> 20;
    const unsigned int* spw = (const unsigned int*)(srt + (size_t)(i >> 8) * SCAP + start);
    int npairs = (deg + 1) >> 1;
    float ax = 0.f, ay = 0.f, az = 0.f;
    for (int w = sub; w < npairs; w += 8) {
        unsigned int u = spw[w];
        float4 v0 = yin[u & 0xFFFF];
        ax += v0.x; ay += v0.y; az += v0.z;
        if (2*w + 1 < deg) {
            float4 v1 = yin[u >> 16];
            ax += v1.x; ay += v1.y; az += v1.z;
        }
    }
    ax += __shfl_xor(ax, 1); ay += __shfl_xor(ay, 1); az += __shfl_xor(az, 1);
    ax += __shfl_xor(ax, 2); ay += __shfl_xor(ay, 2); az += __shfl_xor(az, 2);
    ax += __shfl_xor(ax, 4); ay += __shfl_xor(ay, 4); az += __shfl_xor(az, 4);
    if (sub == 0) {
        float4 self = yin[i];
        float di = dinv[i];
        float a0 = (ax + self.x) * di, a1 = (ay + self.y) * di, a2 = (az + self.z) * di;
        if (first) {
            float h[3];
#pragma unroll
            for (int k = 0; k < 3; k++) {
                float t = a0 * W1[0*3+k] + a1 * W1[1*3+k] + a2 * W1[2*3+k] + b1[k];
                t = (t >= 0.f) ? t : 0.1f * t;
                h[k] = t * di;
            }
            yout[i] = make_float4(h[0], h[1], h[2], 0.f);
        } else {
            yout[i] = make_float4(a0, a1, a2, 0.f);
        }
    }
}

__global__ void k_agg1(const int* __restrict__ rs, const unsigned short* __restrict__ srt,
                       const float* __restrict__ dinv, const float4* __restrict__ y1,
                       const float* __restrict__ W1, const float* __restrict__ b1,
                       float4* __restrict__ y2) {
    agg_pass(blockIdx.x * 256 + threadIdx.x, rs, srt, dinv, W1, b1, y1, y2, true);
}

__global__ void k_agg2(const int* __restrict__ rs, const unsigned short* __restrict__ srt,
                       const float* __restrict__ dinv, const float4* __restrict__ y2,
                       float4* __restrict__ agg2) {
    agg_pass(blockIdx.x * 256 + threadIdx.x, rs, srt, dinv, nullptr, nullptr,
             y2, agg2, false);
}

// Merged head GEMM: each block OWNS its (b,j) outputs (full K) — no partials
// in memory, no second dispatch, no fences. Numerics are bit-identical to the
// old out_part+reduce chain: same 16 s-partials, each accumulated over 16 i's
// ascending, then summed in ascending s onto b3.
__global__ __launch_bounds__(128)
void k_out(const float4* __restrict__ agg2, const float4* __restrict__ V4,
           const float* __restrict__ b3, float* __restrict__ out) {
    __shared__ float4 a_s[BT2 * NPG];             // 4 batches x 256 i = 16 KB
    int tid = threadIdx.x;
    int j  = blockIdx.x * 128 + tid;              // NOUT/128 = 4 j-blocks
    int b0 = blockIdx.y * BT2;
    for (int idx = tid; idx < BT2 * NPG; idx += 128) {
        int t = idx >> 8, i = idx & 255;
        a_s[idx] = agg2[(size_t)(b0 + t) * NPG + i];
    }
    __syncthreads();

    float acc[BT2];
#pragma unroll
    for (int t = 0; t < BT2; t++) acc[t] = b3[j];

    const float4* vj = V4 + j;
    for (int s = 0; s < KS; s++) {
        float ps[BT2];
#pragma unroll
        for (int t = 0; t < BT2; t++) ps[t] = 0.f;
#pragma unroll
        for (int ii = 0; ii < IC; ii++) {
            int i = s * IC + ii;
            float4 vv = vj[(size_t)i * NOUT];
#pragma unroll
            for (int t = 0; t < BT2; t++) {
                float4 a = a_s[t * NPG + i];
                ps[t] += a.x * vv.x + a.y * vv.y + a.z * vv.z + vv.w;
            }
        }
#pragma unroll
        for (int t = 0; t < BT2; t++) acc[t] += ps[t];
    }
#pragma unroll
    for (int t = 0; t < BT2; t++)
        out[(size_t)(b0 + t) * NOUT + j] = acc[t];
}

extern "C" void kernel_launch(void* const* d_in, const int* in_sizes, int n_in,
                              void* d_out, int out_size, void* d_ws, size_t ws_size,
                              hipStream_t stream) {
    const float* nodes = (const float*)d_in[0];
    const int*   ei    = (const int*)  d_in[1];
    const float* W1    = (const float*)d_in[2];
    const float* b1    = (const float*)d_in[3];
    const float* W2    = (const float*)d_in[4];
    const float* b2    = (const float*)d_in[5];
    const float* W3    = (const float*)d_in[6];
    const float* b3    = (const float*)d_in[7];

    const int E = in_sizes[1] / 2;
    const int* src = ei;
    const int* dst = ei + E;
    const int epb = (E + NBIN - 1) / NBIN;

    // Workspace layout (16B-aligned blocks)
    char* ws = (char*)d_ws;
    float4* y1    = (float4*)ws;                              // NN float4 (1 MB)
    float4* y2    = y1 + NN;                                  // 1 MB
    float4* agg2  = y2 + NN;                                  // 1 MB
    float4* V4    = agg2 + NN;                                // NPG*NOUT float4 (2 MB)
    int*    partE = (int*)(V4 + (size_t)NPG * NOUT);          // NBIN*CAP ints (4.7 MB)
    unsigned short* srt = (unsigned short*)(partE + (size_t)NBIN * CAP); // 2.5 MB
    int*    rs    = (int*)(srt + (size_t)NBIN * SCAP);        // 256 KB
    float*  dinv  = (float*)(rs + NN);                        // 256 KB
    int*    cl    = (int*)(dinv + NN);                        // NBIN*NBIN ints (256 KB)

    k_partV<<<2*NBIN,   1024, 0, stream>>>(src, dst, E, partE, cl, W2, b2, W3, V4);
    k_csr  <<<NBIN,      512, 0, stream>>>(cl, partE, epb, nodes, dinv, y1, rs, srt);
    k_agg1 <<<NN*8/256,  256, 0, stream>>>(rs, srt, dinv, y1, W1, b1, y2);
    k_agg2 <<<NN*8/256,  256, 0, stream>>>(rs, srt, dinv, y2, agg2);
    k_out  <<<dim3(NOUT/128, NB/BT2), 128, 0, stream>>>(agg2, V4, b3, (float*)d_out);
}

// Round 7
// 158.696 us; speedup vs baseline: 1.3063x; 1.3063x over previous
//
#include <hip/hip_runtime.h>

// Problem constants (match reference)
static constexpr int NN   = 65536;   // total nodes
static constexpr int NPG  = 256;     // nodes per graph
static constexpr int NB   = 256;     // graphs (batch)
static constexpr int EMB  = 128;     // gcn emb dim
static constexpr int NOUT = 512;     // n_embd

static constexpr int NBIN = 256;     // partitions over dst>>8 (256 nodes each)
static constexpr int CAP  = 4608;    // bin capacity: mean 4096 edges, +8 sigma
static constexpr int SCAP = CAP + 256; // sorted capacity incl. even-padding holes

// Head GEMM tiling: 2048 blocks (8/CU) for latency hiding; numerics identical
// to the BT=16 version (BT only repartitions ownership, not sum grouping).
static constexpr int BT = 8;         // batches per block
static constexpr int KS = 16;        // K-splits over the i axis
static constexpr int IC = NPG / KS;  // 16 i-iterations per block

// clang-native float4 for nontemporal builtins (HIP_vector_type is rejected)
typedef float nfloat4 __attribute__((ext_vector_type(4)));

// Fused partition (blocks 0..255) + buildV (blocks 256..511, 1 V-row each,
// nontemporal float4 W3 loads). V4[i][j] = float4( sum_c W2[k][c]*W3[i*128+c][j],
// k=0..2, b2-row in .w ). packed edge = src | (dst&255)<<16
// Partition output: per-block contiguous (coalesced) + packed (loff|cnt<<16)
// descriptors in cl[blk*NBIN+bin]; no global atomics, no memset needed.
__global__ __launch_bounds__(1024)
void k_partV(const int* __restrict__ src, const int* __restrict__ dst, int E,
             int* __restrict__ part, int* __restrict__ cl,
             const float* __restrict__ W2, const float* __restrict__ b2,
             const float* __restrict__ W3, float4* __restrict__ V4) {
    union SH {
        struct { int hist[NBIN]; int loff[NBIN]; int scanbuf[NBIN];
                 int stage[4096]; } part;                           // ~19.5 KB
        float4 red[8][4][128];                                      // 64 KB
    };
    __shared__ SH sh;
    int tid = threadIdx.x;
    int bid = blockIdx.x;

    if (bid >= NBIN) {
        // ---- buildV role: one i-row, 8 c-groups of 16, nontemporal loads ----
        int i  = bid - NBIN;
        int j4 = tid & 127;
        int cg = tid >> 7;
        const nfloat4* w3 = (const nfloat4*)(W3 + (size_t)i * EMB * NOUT)
                            + (size_t)cg * 16 * (NOUT/4) + j4;
        float4 a0 = {0,0,0,0}, a1 = {0,0,0,0}, a2 = {0,0,0,0}, a3 = {0,0,0,0};
        for (int c = 0; c < 16; c++) {
            nfloat4 v = __builtin_nontemporal_load(&w3[(size_t)c * (NOUT/4)]);
            int cc = cg*16 + c;
            float w0 = W2[0*EMB+cc], w1 = W2[1*EMB+cc], w2 = W2[2*EMB+cc], wb = b2[cc];
            a0.x += w0*v.x; a0.y += w0*v.y; a0.z += w0*v.z; a0.w += w0*v.w;
            a1.x += w1*v.x; a1.y += w1*v.y; a1.z += w1*v.z; a1.w += w1*v.w;
            a2.x += w2*v.x; a2.y += w2*v.y; a2.z += w2*v.z; a2.w += w2*v.w;
            a3.x += wb*v.x; a3.y += wb*v.y; a3.z += wb*v.z; a3.w += wb*v.w;
        }
        sh.red[cg][0][j4] = a0;
        sh.red[cg][1][j4] = a1;
        sh.red[cg][2][j4] = a2;
        sh.red[cg][3][j4] = a3;
        __syncthreads();
        if (tid < 512) {
            int k = tid >> 7, jj = tid & 127;
            float4 s = sh.red[0][k][jj];
#pragma unroll
            for (int g = 1; g < 8; g++) {
                float4 v = sh.red[g][k][jj];
                s.x += v.x; s.y += v.y; s.z += v.z; s.w += v.w;
            }
            sh.red[0][k][jj] = s;
        }
        __syncthreads();
        if (tid < NOUT) {
            int j = tid;
            const float* r0 = (const float*)&sh.red[0][0][j >> 2];
            const float* r1 = (const float*)&sh.red[0][1][j >> 2];
            const float* r2 = (const float*)&sh.red[0][2][j >> 2];
            const float* r3 = (const float*)&sh.red[0][3][j >> 2];
            float4 o = { r0[j & 3], r1[j & 3], r2[j & 3], r3[j & 3] };
            V4[(size_t)i * NOUT + j] = o;
        }
        return;
    }
    // ---- partition role: radix by dst>>8, LDS count+rank, contiguous out ----
    int epb = (E + NBIN - 1) / NBIN;          // 4096 for E=1M
    int e0 = bid * epb;
    int e1 = min(e0 + epb, E);
    if (tid < NBIN) sh.part.hist[tid] = 0;
    __syncthreads();

    int pk[4], bn[4], rk[4];
    int n = 0;
    int e = e0 + tid * 4;
    if (e + 4 <= e1) {
        int4 s4 = *(const int4*)(src + e);
        int4 d4 = *(const int4*)(dst + e);
        int ss[4] = {s4.x, s4.y, s4.z, s4.w};
        int dd[4] = {d4.x, d4.y, d4.z, d4.w};
#pragma unroll
        for (int k = 0; k < 4; k++) {
            pk[k] = ss[k] | ((dd[k] & 255) << 16);
            bn[k] = dd[k] >> 8;
            rk[k] = atomicAdd(&sh.part.hist[bn[k]], 1);
        }
        n = 4;
    } else {
        for (int k = 0; k < 4 && e + k < e1; k++) {
            int s = src[e+k], d = dst[e+k];
            pk[n] = s | ((d & 255) << 16);
            bn[n] = d >> 8;
            rk[n] = atomicAdd(&sh.part.hist[bn[n]], 1);
            n++;
        }
    }
    __syncthreads();

    if (tid < NBIN) sh.part.scanbuf[tid] = sh.part.hist[tid];
    __syncthreads();
    for (int off = 1; off < NBIN; off <<= 1) {
        int v = 0;
        if (tid < NBIN && tid >= off) v = sh.part.scanbuf[tid - off];
        __syncthreads();
        if (tid < NBIN) sh.part.scanbuf[tid] += v;
        __syncthreads();
    }
    if (tid < NBIN) {
        int lo = sh.part.scanbuf[tid] - sh.part.hist[tid];
        sh.part.loff[tid] = lo;
        cl[bid * NBIN + tid] = lo | (sh.part.hist[tid] << 16);  // coalesced
    }
    __syncthreads();

    for (int k = 0; k < n; k++) sh.part.stage[sh.part.loff[bn[k]] + rk[k]] = pk[k];
    __syncthreads();

    int ctot = e1 - e0;                       // all edges staged, dense
    for (int t = tid; t < ctot; t += 1024)
        part[(size_t)bid * epb + t] = sh.part.stage[t];         // coalesced
}

// Per-bin CSR build (counting sort by dst) + degprep fused. 512 threads.
// Gathers this bin's edge segments from all 256 partition blocks using the
// packed (loff|cnt) descriptors; per-blk bases via 64-wide wave scan.
// Node starts even-padded so neighbor lists are uint-aligned for the gathers.
__global__ __launch_bounds__(512)
void k_csr(const int* __restrict__ cl, const int* __restrict__ part, int epb,
           const float* __restrict__ nodes,
           float* __restrict__ dinv, float4* __restrict__ y1,
           int* __restrict__ rs, unsigned short* __restrict__ srt) {
    __shared__ int pkst[CAP];
    __shared__ int hist[NPG], off_[NPG];
    __shared__ int wtot[4];
    __shared__ int cls[NBIN], blo[NBIN];
    __shared__ unsigned short stageS[SCAP];
    int tid = threadIdx.x, bin = blockIdx.x;
    if (tid < NPG) hist[tid] = 0;

    // per-blk counts for this bin; exclusive scan over 256 blks
    int cn = 0, v = 0;
    if (tid < NBIN) {
        int c = cl[tid * NBIN + bin];
        cls[tid] = c;
        cn = c >> 16;
        v = cn;
    }
    int lane = tid & 63;
#pragma unroll
    for (int off = 1; off < 64; off <<= 1) {
        int t = __shfl_up(v, off, 64);
        if (tid < NBIN && lane >= off) v += t;
    }
    if (tid < NBIN && lane == 63) wtot[tid >> 6] = v;
    __syncthreads();                                   // B1
    if (tid < NBIN) {
        int wv = tid >> 6, offs = 0;
#pragma unroll
        for (int w = 0; w < 3; w++) if (w < wv) offs += wtot[w];
        blo[tid] = v + offs - cn;                      // exclusive base
    }
    __syncthreads();                                   // B2

    // copy + per-node count: 2 threads per partition block
    {
        int blk = tid >> 1, half = tid & 1;
        int c = cls[blk];
        int lo = c & 0xFFFF, cb = c >> 16;
        int db = blo[blk];
        const int* q = part + (size_t)blk * epb + lo;
        for (int t = half; t < cb; t += 2) {
            int d2 = db + t;
            if (d2 < CAP) {
                int p = q[t];
                pkst[d2] = p;
                atomicAdd(&hist[(p >> 16) & 255], 1);
            }
        }
    }
    __syncthreads();                                   // B3

    // wave-scan of even-padded per-node counts
    int h = 0, v2 = 0;
    if (tid < NPG) { h = hist[tid]; v2 = (h + 1) & ~1; }
#pragma unroll
    for (int off = 1; off < 64; off <<= 1) {
        int t = __shfl_up(v2, off, 64);
        if (tid < NPG && lane >= off) v2 += t;
    }
    if (tid < NPG && lane == 63) wtot[tid >> 6] = v2;
    __syncthreads();
    if (tid < NPG) {
        int wv = tid >> 6;
        int offs = 0;
#pragma unroll
        for (int w = 0; w < 3; w++) if (w < wv) offs += wtot[w];
        int start = v2 + offs - ((h + 1) & ~1);     // exclusive even-padded start
        off_[tid] = start;
        int node = bin * NPG + tid;
        float di = rsqrtf((float)(h + 1));          // +1 self-loop
        dinv[node] = di;
        y1[node] = make_float4(nodes[3*node+0] * di, nodes[3*node+1] * di,
                               nodes[3*node+2] * di, 0.f);
        rs[node] = start | (h << 20);
    }
    __syncthreads();
    int rawtot = blo[NBIN-1] + (cls[NBIN-1] >> 16);
    if (rawtot > CAP) rawtot = CAP;
    for (int e2 = tid; e2 < rawtot; e2 += 512) {
        int p = pkst[e2];
        int pos = atomicAdd(&off_[(p >> 16) & 255], 1);
        stageS[pos] = (unsigned short)(p & 0xFFFF);
    }
    __syncthreads();
    int tot = wtot[0] + wtot[1] + wtot[2] + wtot[3];   // even-padded total
    const unsigned int* so = (const unsigned int*)stageS;
    unsigned int* g = (unsigned int*)(srt + (size_t)bin * SCAP);
    for (int t = tid; t < (tot >> 1); t += 512) g[t] = so[t];
}

// Octet-per-node CSR gather: one coalesced uint = 2 neighbor ids per lane,
// both y-gathers issue independently (1 dependent round instead of 2).
__device__ __forceinline__ void agg_pass(int g, const int* __restrict__ rs,
                                         const unsigned short* __restrict__ srt,
                                         const float* __restrict__ dinv,
                                         const float* __restrict__ W1,
                                         const float* __restrict__ b1,
                                         const float4* __restrict__ yin,
                                         float4* __restrict__ yout, bool first) {
    int i = g >> 3, sub = g & 7;
    int rsd = rs[i];
    int start = rsd & 0xFFFFF, deg = rsd >> 20;
    const unsigned int* spw = (const unsigned int*)(srt + (size_t)(i >> 8) * SCAP + start);
    int npairs = (deg + 1) >> 1;
    float ax = 0.f, ay = 0.f, az = 0.f;
    for (int w = sub; w < npairs; w += 8) {
        unsigned int u = spw[w];
        float4 v0 = yin[u & 0xFFFF];
        ax += v0.x; ay += v0.y; az += v0.z;
        if (2*w + 1 < deg) {
            float4 v1 = yin[u >> 16];
            ax += v1.x; ay += v1.y; az += v1.z;
        }
    }
    ax += __shfl_xor(ax, 1); ay += __shfl_xor(ay, 1); az += __shfl_xor(az, 1);
    ax += __shfl_xor(ax, 2); ay += __shfl_xor(ay, 2); az += __shfl_xor(az, 2);
    ax += __shfl_xor(ax, 4); ay += __shfl_xor(ay, 4); az += __shfl_xor(az, 4);
    if (sub == 0) {
        float4 self = yin[i];
        float di = dinv[i];
        float a0 = (ax + self.x) * di, a1 = (ay + self.y) * di, a2 = (az + self.z) * di;
        if (first) {
            float h[3];
#pragma unroll
            for (int k = 0; k < 3; k++) {
                float t = a0 * W1[0*3+k] + a1 * W1[1*3+k] + a2 * W1[2*3+k] + b1[k];
                t = (t >= 0.f) ? t : 0.1f * t;
                h[k] = t * di;
            }
            yout[i] = make_float4(h[0], h[1], h[2], 0.f);
        } else {
            yout[i] = make_float4(a0, a1, a2, 0.f);
        }
    }
}

__global__ void k_agg1(const int* __restrict__ rs, const unsigned short* __restrict__ srt,
                       const float* __restrict__ dinv, const float4* __restrict__ y1,
                       const float* __restrict__ W1, const float* __restrict__ b1,
                       float4* __restrict__ y2) {
    agg_pass(blockIdx.x * 256 + threadIdx.x, rs, srt, dinv, W1, b1, y1, y2, true);
}

__global__ void k_agg2(const int* __restrict__ rs, const unsigned short* __restrict__ srt,
                       const float* __restrict__ dinv, const float4* __restrict__ y2,
                       float4* __restrict__ agg2) {
    agg_pass(blockIdx.x * 256 + threadIdx.x, rs, srt, dinv, nullptr, nullptr,
             y2, agg2, false);
}

// Split-K head: 2048 blocks (8/CU) of 128 threads. One float4 V-load per (i,j).
// No fences — k_reduce (separate dispatch) consumes the partials; stream order
// gives visibility. Partial sums bit-identical to the BT=16 version.
__global__ __launch_bounds__(128)
void k_out_part(const float4* __restrict__ agg2, const float4* __restrict__ V4,
                float* __restrict__ partO) {
    __shared__ float4 a_s[BT * IC];               // 128 float4 = 2 KB
    int tid = threadIdx.x;
    int j  = blockIdx.x * 128 + tid;              // 4 j-blocks
    int b0 = blockIdx.y * BT;
    int i0 = blockIdx.z * IC;
    {
        int t = tid >> 4, i = tid & 15;           // 128 threads = BT*IC exactly
        a_s[tid] = agg2[(size_t)(b0 + t) * NPG + i0 + i];
    }
    __syncthreads();

    float acc[BT];
#pragma unroll
    for (int t = 0; t < BT; t++) acc[t] = 0.f;

    const float4* vj = V4 + (size_t)i0 * NOUT + j;
#pragma unroll
    for (int i = 0; i < IC; i++) {
        float4 vv = vj[(size_t)i * NOUT];
#pragma unroll
        for (int t = 0; t < BT; t++) {
            float4 a = a_s[t*IC + i];
            acc[t] += a.x * vv.x + a.y * vv.y + a.z * vv.z + vv.w;
        }
    }
#pragma unroll
    for (int t = 0; t < BT; t++)
        partO[((size_t)blockIdx.z * NB + b0 + t) * NOUT + j] = acc[t];
}

// out = b3 + sum_s part[s]  (float4-vectorized, fixed s-order)
__global__ void k_reduce(const float4* __restrict__ part4, const float4* __restrict__ b3_4,
                         float4* __restrict__ out4) {
    int idx = blockIdx.x * 256 + threadIdx.x;     // over NB*NOUT/4 = 32768
    int j4 = idx & (NOUT/4 - 1);
    float4 acc = b3_4[j4];
#pragma unroll
    for (int s = 0; s < KS; s++) {
        float4 v = part4[(size_t)s * (NB*NOUT/4) + idx];
        acc.x += v.x; acc.y += v.y; acc.z += v.z; acc.w += v.w;
    }
    out4[idx] = acc;
}

extern "C" void kernel_launch(void* const* d_in, const int* in_sizes, int n_in,
                              void* d_out, int out_size, void* d_ws, size_t ws_size,
                              hipStream_t stream) {
    const float* nodes = (const float*)d_in[0];
    const int*   ei    = (const int*)  d_in[1];
    const float* W1    = (const float*)d_in[2];
    const float* b1    = (const float*)d_in[3];
    const float* W2    = (const float*)d_in[4];
    const float* b2    = (const float*)d_in[5];
    const float* W3    = (const float*)d_in[6];
    const float* b3    = (const float*)d_in[7];

    const int E = in_sizes[1] / 2;
    const int* src = ei;
    const int* dst = ei + E;
    const int epb = (E + NBIN - 1) / NBIN;

    // Workspace layout (16B-aligned blocks)
    char* ws = (char*)d_ws;
    float4* y1    = (float4*)ws;                              // NN float4 (1 MB)
    float4* y2    = y1 + NN;                                  // 1 MB
    float4* agg2  = y2 + NN;                                  // 1 MB
    float4* V4    = agg2 + NN;                                // NPG*NOUT float4 (2 MB)
    float*  partO = (float*)(V4 + (size_t)NPG * NOUT);        // KS*NB*NOUT (8 MB)
    int*    partE = (int*)(partO + (size_t)KS * NB * NOUT);   // NBIN*CAP ints (4.7 MB)
    unsigned short* srt = (unsigned short*)(partE + (size_t)NBIN * CAP); // 2.5 MB
    int*    rs    = (int*)(srt + (size_t)NBIN * SCAP);        // 256 KB
    float*  dinv  = (float*)(rs + NN);                        // 256 KB
    int*    cl    = (int*)(dinv + NN);                        // NBIN*NBIN ints (256 KB)

    k_partV   <<<2*NBIN,   1024, 0, stream>>>(src, dst, E, partE, cl, W2, b2, W3, V4);
    k_csr     <<<NBIN,      512, 0, stream>>>(cl, partE, epb, nodes, dinv, y1, rs, srt);
    k_agg1    <<<NN*8/256,  256, 0, stream>>>(rs, srt, dinv, y1, W1, b1, y2);
    k_agg2    <<<NN*8/256,  256, 0, stream>>>(rs, srt, dinv, y2, agg2);
    k_out_part<<<dim3(4, NB/BT, KS), 128, 0, stream>>>(agg2, V4, partO);
    k_reduce  <<<NB*NOUT/4/256,      256, 0, stream>>>((const float4*)partO,
                                                       (const float4*)b3, (float4*)d_out);
}

// Round 8
// 154.687 us; speedup vs baseline: 1.3401x; 1.0259x over previous
//
#include <hip/hip_runtime.h>

// Problem constants (match reference)
static constexpr int NN   = 65536;   // total nodes
static constexpr int NPG  = 256;     // nodes per graph
static constexpr int NB   = 256;     // graphs (batch)
static constexpr int EMB  = 128;     // gcn emb dim
static constexpr int NOUT = 512;     // n_embd

static constexpr int NBIN = 256;     // partitions over dst>>8 (256 nodes each)
static constexpr int CAP  = 4608;    // bin capacity: mean 4096 edges, +8 sigma
static constexpr int SCAP = CAP + 256; // sorted capacity incl. even-padding holes

// Head GEMM tiling
static constexpr int BT = 16;        // batches per block (16: halves V re-read)
static constexpr int KS = 16;        // K-splits over the i axis
static constexpr int IC = NPG / KS;  // 16 i-iterations per block

// Fused partition (blocks 0..255) + buildV (blocks 256..511, 1 V-row each,
// float4 W3 loads). V4[i][j] = float4( sum_c W2[k][c]*W3[i*128+c][j], k=0..2,
// b2-row in .w ). packed edge = src | (dst&255)<<16
// Partition output: per-block contiguous (coalesced) + packed (loff|cnt<<16)
// descriptors in cl[blk*NBIN+bin]; no global atomics, no memset needed.
__global__ __launch_bounds__(1024)
void k_partV(const int* __restrict__ src, const int* __restrict__ dst, int E,
             int* __restrict__ part, int* __restrict__ cl,
             const float* __restrict__ W2, const float* __restrict__ b2,
             const float* __restrict__ W3, float4* __restrict__ V4) {
    union SH {
        struct { int hist[NBIN]; int loff[NBIN]; int scanbuf[NBIN];
                 int stage[4096]; } part;                           // ~19.5 KB
        float4 red[8][4][128];                                      // 64 KB
    };
    __shared__ SH sh;
    int tid = threadIdx.x;
    int bid = blockIdx.x;

    if (bid >= NBIN) {
        // ---- buildV role: one i-row, float4 loads, 8 c-groups of 16 ----
        int i  = bid - NBIN;
        int j4 = tid & 127;
        int cg = tid >> 7;
        const float4* w3 = (const float4*)(W3 + (size_t)i * EMB * NOUT)
                           + (size_t)cg * 16 * (NOUT/4) + j4;
        float4 a0 = {0,0,0,0}, a1 = {0,0,0,0}, a2 = {0,0,0,0}, a3 = {0,0,0,0};
        for (int c = 0; c < 16; c++) {
            float4 v = w3[(size_t)c * (NOUT/4)];
            int cc = cg*16 + c;
            float w0 = W2[0*EMB+cc], w1 = W2[1*EMB+cc], w2 = W2[2*EMB+cc], wb = b2[cc];
            a0.x += w0*v.x; a0.y += w0*v.y; a0.z += w0*v.z; a0.w += w0*v.w;
            a1.x += w1*v.x; a1.y += w1*v.y; a1.z += w1*v.z; a1.w += w1*v.w;
            a2.x += w2*v.x; a2.y += w2*v.y; a2.z += w2*v.z; a2.w += w2*v.w;
            a3.x += wb*v.x; a3.y += wb*v.y; a3.z += wb*v.z; a3.w += wb*v.w;
        }
        sh.red[cg][0][j4] = a0;
        sh.red[cg][1][j4] = a1;
        sh.red[cg][2][j4] = a2;
        sh.red[cg][3][j4] = a3;
        __syncthreads();
        if (tid < 512) {
            int k = tid >> 7, jj = tid & 127;
            float4 s = sh.red[0][k][jj];
#pragma unroll
            for (int g = 1; g < 8; g++) {
                float4 v = sh.red[g][k][jj];
                s.x += v.x; s.y += v.y; s.z += v.z; s.w += v.w;
            }
            sh.red[0][k][jj] = s;
        }
        __syncthreads();
        if (tid < NOUT) {
            int j = tid;
            const float* r0 = (const float*)&sh.red[0][0][j >> 2];
            const float* r1 = (const float*)&sh.red[0][1][j >> 2];
            const float* r2 = (const float*)&sh.red[0][2][j >> 2];
            const float* r3 = (const float*)&sh.red[0][3][j >> 2];
            float4 o = { r0[j & 3], r1[j & 3], r2[j & 3], r3[j & 3] };
            V4[(size_t)i * NOUT + j] = o;
        }
        return;
    }
    // ---- partition role: radix by dst>>8, LDS count+rank, contiguous out ----
    int epb = (E + NBIN - 1) / NBIN;          // 4096 for E=1M
    int e0 = bid * epb;
    int e1 = min(e0 + epb, E);
    if (tid < NBIN) sh.part.hist[tid] = 0;
    __syncthreads();

    int pk[4], bn[4], rk[4];
    int n = 0;
    int e = e0 + tid * 4;
    if (e + 4 <= e1) {
        int4 s4 = *(const int4*)(src + e);
        int4 d4 = *(const int4*)(dst + e);
        int ss[4] = {s4.x, s4.y, s4.z, s4.w};
        int dd[4] = {d4.x, d4.y, d4.z, d4.w};
#pragma unroll
        for (int k = 0; k < 4; k++) {
            pk[k] = ss[k] | ((dd[k] & 255) << 16);
            bn[k] = dd[k] >> 8;
            rk[k] = atomicAdd(&sh.part.hist[bn[k]], 1);
        }
        n = 4;
    } else {
        for (int k = 0; k < 4 && e + k < e1; k++) {
            int s = src[e+k], d = dst[e+k];
            pk[n] = s | ((d & 255) << 16);
            bn[n] = d >> 8;
            rk[n] = atomicAdd(&sh.part.hist[bn[n]], 1);
            n++;
        }
    }
    __syncthreads();

    if (tid < NBIN) sh.part.scanbuf[tid] = sh.part.hist[tid];
    __syncthreads();
    for (int off = 1; off < NBIN; off <<= 1) {
        int v = 0;
        if (tid < NBIN && tid >= off) v = sh.part.scanbuf[tid - off];
        __syncthreads();
        if (tid < NBIN) sh.part.scanbuf[tid] += v;
        __syncthreads();
    }
    if (tid < NBIN) {
        int lo = sh.part.scanbuf[tid] - sh.part.hist[tid];
        sh.part.loff[tid] = lo;
        cl[bid * NBIN + tid] = lo | (sh.part.hist[tid] << 16);  // coalesced
    }
    __syncthreads();

    for (int k = 0; k < n; k++) sh.part.stage[sh.part.loff[bn[k]] + rk[k]] = pk[k];
    __syncthreads();

    int ctot = e1 - e0;                       // all edges staged, dense
    for (int t = tid; t < ctot; t += 1024)
        part[(size_t)bid * epb + t] = sh.part.stage[t];         // coalesced
}

// Per-bin CSR build (counting sort by dst) + degprep fused. 512 threads.
// Gathers this bin's edge segments from all 256 partition blocks using the
// packed (loff|cnt) descriptors; per-blk bases via 64-wide wave scan.
// Node starts even-padded so neighbor lists are uint-aligned for the gathers.
__global__ __launch_bounds__(512)
void k_csr(const int* __restrict__ cl, const int* __restrict__ part, int epb,
           const float* __restrict__ nodes,
           float* __restrict__ dinv, float4* __restrict__ y1,
           int* __restrict__ rs, unsigned short* __restrict__ srt) {
    __shared__ int pkst[CAP];
    __shared__ int hist[NPG], off_[NPG];
    __shared__ int wtot[4];
    __shared__ int cls[NBIN], blo[NBIN];
    __shared__ unsigned short stageS[SCAP];
    int tid = threadIdx.x, bin = blockIdx.x;
    if (tid < NPG) hist[tid] = 0;

    // per-blk counts for this bin; exclusive scan over 256 blks
    int cn = 0, v = 0;
    if (tid < NBIN) {
        int c = cl[tid * NBIN + bin];
        cls[tid] = c;
        cn = c >> 16;
        v = cn;
    }
    int lane = tid & 63;
#pragma unroll
    for (int off = 1; off < 64; off <<= 1) {
        int t = __shfl_up(v, off, 64);
        if (tid < NBIN && lane >= off) v += t;
    }
    if (tid < NBIN && lane == 63) wtot[tid >> 6] = v;
    __syncthreads();                                   // B1
    if (tid < NBIN) {
        int wv = tid >> 6, offs = 0;
#pragma unroll
        for (int w = 0; w < 3; w++) if (w < wv) offs += wtot[w];
        blo[tid] = v + offs - cn;                      // exclusive base
    }
    __syncthreads();                                   // B2

    // copy + per-node count: 2 threads per partition block
    {
        int blk = tid >> 1, half = tid & 1;
        int c = cls[blk];
        int lo = c & 0xFFFF, cb = c >> 16;
        int db = blo[blk];
        const int* q = part + (size_t)blk * epb + lo;
        for (int t = half; t < cb; t += 2) {
            int d2 = db + t;
            if (d2 < CAP) {
                int p = q[t];
                pkst[d2] = p;
                atomicAdd(&hist[(p >> 16) & 255], 1);
            }
        }
    }
    __syncthreads();                                   // B3

    // wave-scan of even-padded per-node counts
    int h = 0, v2 = 0;
    if (tid < NPG) { h = hist[tid]; v2 = (h + 1) & ~1; }
#pragma unroll
    for (int off = 1; off < 64; off <<= 1) {
        int t = __shfl_up(v2, off, 64);
        if (tid < NPG && lane >= off) v2 += t;
    }
    if (tid < NPG && lane == 63) wtot[tid >> 6] = v2;
    __syncthreads();
    if (tid < NPG) {
        int wv = tid >> 6;
        int offs = 0;
#pragma unroll
        for (int w = 0; w < 3; w++) if (w < wv) offs += wtot[w];
        int start = v2 + offs - ((h + 1) & ~1);     // exclusive even-padded start
        off_[tid] = start;
        int node = bin * NPG + tid;
        float di = rsqrtf((float)(h + 1));          // +1 self-loop
        dinv[node] = di;
        y1[node] = make_float4(nodes[3*node+0] * di, nodes[3*node+1] * di,
                               nodes[3*node+2] * di, 0.f);
        rs[node] = start | (h << 20);
    }
    __syncthreads();
    int rawtot = blo[NBIN-1] + (cls[NBIN-1] >> 16);
    if (rawtot > CAP) rawtot = CAP;
    for (int e2 = tid; e2 < rawtot; e2 += 512) {
        int p = pkst[e2];
        int pos = atomicAdd(&off_[(p >> 16) & 255], 1);
        stageS[pos] = (unsigned short)(p & 0xFFFF);
    }
    __syncthreads();
    int tot = wtot[0] + wtot[1] + wtot[2] + wtot[3];   // even-padded total
    const unsigned int* so = (const unsigned int*)stageS;
    unsigned int* g = (unsigned int*)(srt + (size_t)bin * SCAP);
    for (int t = tid; t < (tot >> 1); t += 512) g[t] = so[t];
}

// Octet-per-node CSR gather: one coalesced uint = 2 neighbor ids per lane,
// both y-gathers issue independently (1 dependent round instead of 2).
__device__ __forceinline__ void agg_pass(int g, const int* __restrict__ rs,
                                         const unsigned short* __restrict__ srt,
                                         const float* __restrict__ dinv,
                                         const float* __restrict__ W1,
                                         const float* __restrict__ b1,
                                         const float4* __restrict__ yin,
                                         float4* __restrict__ yout, bool first) {
    int i = g >> 3, sub = g & 7;
    int rsd = rs[i];
    int start = rsd & 0xFFFFF, deg = rsd >> 20;
    const unsigned int* spw = (const unsigned int*)(srt + (size_t)(i >> 8) * SCAP + start);
    int npairs = (deg + 1) >> 1;
    float ax = 0.f, ay = 0.f, az = 0.f;
    for (int w = sub; w < npairs; w += 8) {
        unsigned int u = spw[w];
        float4 v0 = yin[u & 0xFFFF];
        ax += v0.x; ay += v0.y; az += v0.z;
        if (2*w + 1 < deg) {
            float4 v1 = yin[u >> 16];
            ax += v1.x; ay += v1.y; az += v1.z;
        }
    }
    ax += __shfl_xor(ax, 1); ay += __shfl_xor(ay, 1); az += __shfl_xor(az, 1);
    ax += __shfl_xor(ax, 2); ay += __shfl_xor(ay, 2); az += __shfl_xor(az, 2);
    ax += __shfl_xor(ax, 4); ay += __shfl_xor(ay, 4); az += __shfl_xor(az, 4);
    if (sub == 0) {
        float4 self = yin[i];
        float di = dinv[i];
        float a0 = (ax + self.x) * di, a1 = (ay + self.y) * di, a2 = (az + self.z) * di;
        if (first) {
            float h[3];
#pragma unroll
            for (int k = 0; k < 3; k++) {
                float t = a0 * W1[0*3+k] + a1 * W1[1*3+k] + a2 * W1[2*3+k] + b1[k];
                t = (t >= 0.f) ? t : 0.1f * t;
                h[k] = t * di;
            }
            yout[i] = make_float4(h[0], h[1], h[2], 0.f);
        } else {
            yout[i] = make_float4(a0, a1, a2, 0.f);
        }
    }
}

__global__ void k_agg1(const int* __restrict__ rs, const unsigned short* __restrict__ srt,
                       const float* __restrict__ dinv, const float4* __restrict__ y1,
                       const float* __restrict__ W1, const float* __restrict__ b1,
                       float4* __restrict__ y2) {
    agg_pass(blockIdx.x * 256 + threadIdx.x, rs, srt, dinv, W1, b1, y1, y2, true);
}

__global__ void k_agg2(const int* __restrict__ rs, const unsigned short* __restrict__ srt,
                       const float* __restrict__ dinv, const float4* __restrict__ y2,
                       float4* __restrict__ agg2) {
    agg_pass(blockIdx.x * 256 + threadIdx.x, rs, srt, dinv, nullptr, nullptr,
             y2, agg2, false);
}

// Split-K head: one float4 V-load per (i,j). No fences — k_reduce (separate
// dispatch) consumes the partials; stream order gives visibility.
__global__ void k_out_part(const float4* __restrict__ agg2, const float4* __restrict__ V4,
                           float* __restrict__ partO) {
    __shared__ float4 a_s[BT * IC];
    int tid = threadIdx.x;
    int j  = blockIdx.x * 256 + tid;
    int b0 = blockIdx.y * BT;
    int i0 = blockIdx.z * IC;
    for (int idx = tid; idx < BT * IC; idx += 256) {
        int t = idx / IC, i = idx % IC;
        a_s[idx] = agg2[(size_t)(b0 + t) * NPG + i0 + i];
    }
    __syncthreads();

    float acc[BT];
#pragma unroll
    for (int t = 0; t < BT; t++) acc[t] = 0.f;

    const float4* vj = V4 + (size_t)i0 * NOUT + j;
    for (int i = 0; i < IC; i++) {
        float4 vv = vj[(size_t)i * NOUT];
#pragma unroll
        for (int t = 0; t < BT; t++) {
            float4 a = a_s[t*IC + i];
            acc[t] += a.x * vv.x + a.y * vv.y + a.z * vv.z + vv.w;
        }
    }
#pragma unroll
    for (int t = 0; t < BT; t++)
        partO[((size_t)blockIdx.z * NB + b0 + t) * NOUT + j] = acc[t];
}

// out = b3 + sum_s part[s]  (float4-vectorized, fixed s-order)
__global__ void k_reduce(const float4* __restrict__ part4, const float4* __restrict__ b3_4,
                         float4* __restrict__ out4) {
    int idx = blockIdx.x * 256 + threadIdx.x;     // over NB*NOUT/4 = 32768
    int j4 = idx & (NOUT/4 - 1);
    float4 acc = b3_4[j4];
#pragma unroll
    for (int s = 0; s < KS; s++) {
        float4 v = part4[(size_t)s * (NB*NOUT/4) + idx];
        acc.x += v.x; acc.y += v.y; acc.z += v.z; acc.w += v.w;
    }
    out4[idx] = acc;
}

extern "C" void kernel_launch(void* const* d_in, const int* in_sizes, int n_in,
                              void* d_out, int out_size, void* d_ws, size_t ws_size,
                              hipStream_t stream) {
    const float* nodes = (const float*)d_in[0];
    const int*   ei    = (const int*)  d_in[1];
    const float* W1    = (const float*)d_in[2];
    const float* b1    = (const float*)d_in[3];
    const float* W2    = (const float*)d_in[4];
    const float* b2    = (const float*)d_in[5];
    const float* W3    = (const float*)d_in[6];
    const float* b3    = (const float*)d_in[7];

    const int E = in_sizes[1] / 2;
    const int* src = ei;
    const int* dst = ei + E;
    const int epb = (E + NBIN - 1) / NBIN;

    // Workspace layout (16B-aligned blocks)
    char* ws = (char*)d_ws;
    float4* y1    = (float4*)ws;                              // NN float4 (1 MB)
    float4* y2    = y1 + NN;                                  // 1 MB
    float4* agg2  = y2 + NN;                                  // 1 MB
    float4* V4    = agg2 + NN;                                // NPG*NOUT float4 (2 MB)
    float*  partO = (float*)(V4 + (size_t)NPG * NOUT);        // KS*NB*NOUT (8 MB)
    int*    partE = (int*)(partO + (size_t)KS * NB * NOUT);   // NBIN*CAP ints (4.7 MB)
    unsigned short* srt = (unsigned short*)(partE + (size_t)NBIN * CAP); // 2.5 MB
    int*    rs    = (int*)(srt + (size_t)NBIN * SCAP);        // 256 KB
    float*  dinv  = (float*)(rs + NN);                        // 256 KB
    int*    cl    = (int*)(dinv + NN);                        // NBIN*NBIN ints (256 KB)

    k_partV   <<<2*NBIN, 1024, 0, stream>>>(src, dst, E, partE, cl, W2, b2, W3, V4);
    k_csr     <<<NBIN,    512, 0, stream>>>(cl, partE, epb, nodes, dinv, y1, rs, srt);
    k_agg1    <<<NN*8/256, 256, 0, stream>>>(rs, srt, dinv, y1, W1, b1, y2);
    k_agg2    <<<NN*8/256, 256, 0, stream>>>(rs, srt, dinv, y2, agg2);
    k_out_part<<<dim3(2, NB/BT, KS), 256, 0, stream>>>(agg2, V4, partO);
    k_reduce  <<<NB*NOUT/4/256,      256, 0, stream>>>((const float4*)partO,
                                                       (const float4*)b3, (float4*)d_out);
}